// Round 3
// baseline (552.698 us; speedup 1.0000x reference)
//
#include <hip/hip_runtime.h>
#include <hip/hip_bf16.h>

#define E_ 8
#define H_ 2048
#define I_ 5632
#define B_ 1024
#define K_ 2
#define NROWS (B_*K_)

#define BM 128
#define BN 128
#define BK 64
#define MAXT 24          // sum_e ceil(cnt_e/BM) <= 16 + 8
#define NKG (H_/BK)      // 32
#define NKD (I_/BK)      // 88

typedef __attribute__((ext_vector_type(8))) __bf16 bf16x8;
typedef __attribute__((ext_vector_type(4))) float f32x4;

union BF8 { __bf16 b[8]; uint4 q; };

__device__ __forceinline__ void gld_lds16(const void* g, void* l) {
  __builtin_amdgcn_global_load_lds(
      (const __attribute__((address_space(1))) void*)g,
      (__attribute__((address_space(3))) void*)l, 16, 0, 0);
}

// ---------------- phase 0: x (f32) -> xb (bf16) ----------------
__global__ void cvtx_kernel(const float* __restrict__ x, __bf16* __restrict__ xb) {
  int i = (blockIdx.x * 256 + threadIdx.x) * 8;
  float4 a = *(const float4*)(x + i);
  float4 b = *(const float4*)(x + i + 4);
  BF8 r;
  r.b[0] = (__bf16)a.x; r.b[1] = (__bf16)a.y; r.b[2] = (__bf16)a.z; r.b[3] = (__bf16)a.w;
  r.b[4] = (__bf16)b.x; r.b[5] = (__bf16)b.y; r.b[6] = (__bf16)b.z; r.b[7] = (__bf16)b.w;
  *(uint4*)(xb + i) = r.q;
}

// ---------------- phase 1: routing + dense tile list ----------------
__global__ void route_kernel(const int* __restrict__ ids,
                             int* __restrict__ counts, int* __restrict__ offsets,
                             int* __restrict__ tlist, int* __restrict__ row_of,
                             int* __restrict__ tile_e, int* __restrict__ tile_m) {
  __shared__ int sc[E_], sp[E_], so[E_];
  int t = threadIdx.x;
  if (t < E_) { sc[t] = 0; sp[t] = 0; }
  __syncthreads();
  for (int idx = t; idx < NROWS; idx += 256) atomicAdd(&sc[ids[idx]], 1);
  __syncthreads();
  if (t == 0) {
    int acc = 0;
    for (int e = 0; e < E_; ++e) { so[e] = acc; acc += sc[e]; }
    int nt = 0;
    for (int e = 0; e < E_; ++e)
      for (int m0 = 0; m0 < sc[e]; m0 += BM) { tile_e[nt] = e; tile_m[nt] = m0; ++nt; }
    for (; nt < MAXT; ++nt) { tile_e[nt] = 0; tile_m[nt] = 0x7FFFFFFF; }
  }
  __syncthreads();
  for (int idx = t; idx < NROWS; idx += 256) {
    int e = ids[idx];
    int slot = atomicAdd(&sp[e], 1);
    int row = so[e] + slot;
    tlist[row] = idx / K_;
    row_of[idx] = row;
  }
  if (t < E_) { counts[t] = sc[t]; offsets[t] = so[t]; }
}

// ---------------- phase 2: gate+up dual GEMM + SiLU (bf16 act) ----------------
// 512 threads (8 waves, 2x4 over 128x128 tile), LDS double-buffered (96 KB),
// B weights reg-prefetched one K-tile ahead; A via global_load_lds one ahead.
__global__ __launch_bounds__(512, 1) void gateup_kernel(
    const __bf16* __restrict__ xb, const float* __restrict__ gw,
    const float* __restrict__ uw, const int* __restrict__ counts,
    const int* __restrict__ offsets, const int* __restrict__ tlist,
    const int* __restrict__ tile_e, const int* __restrict__ tile_m,
    __bf16* __restrict__ act)
{
  extern __shared__ __bf16 smem[];
  __bf16* As  = smem;              // [2][8192]
  __bf16* Bgs = smem + 16384;      // [2][8192]
  __bf16* Bus = smem + 32768;      // [2][8192]

  const int id = blockIdx.x;                    // [0, 1056)
  const int w  = (id & 7) * 132 + (id >> 3);    // XCD-pairing bijection
  const int tt = w % MAXT;
  const int ny = w / MAXT;                      // [0, 44)
  const int e  = tile_e[tt];
  const int m0 = tile_m[tt];
  const int cnt = counts[e];
  if (m0 >= cnt) return;
  const int off = offsets[e];
  const int n0 = ny * BN;

  const int tid  = threadIdx.x;
  const int lane = tid & 63;
  const int wave = tid >> 6;            // 0..7
  const int wr = (wave >> 2) * 64;      // 0,64
  const int wc = (wave & 3) * 32;       // 0,32,64,96

  // A staging: 2 issues x 16B per thread, LDS linear, source slot-swizzled
  const __bf16* asrc[2];
  int adoff[2];
#pragma unroll
  for (int i = 0; i < 2; ++i) {
    int f = i*512 + tid;
    int r = f >> 3, cs = f & 7;
    int rr = m0 + r; if (rr >= cnt) rr = cnt - 1;
    int tok = tlist[off + rr];
    asrc[i] = xb + (size_t)tok * H_ + ((cs ^ (r & 7)) << 3);
    adoff[i] = f * 8;
  }

  // B staging: thread owns cols c0,c0+1; k-rows kq*8 .. kq*8+7
  const int c0 = (tid & 63) * 2;
  const int kq = wave;
  const float* gsrc = gw + ((size_t)e*H_ + (size_t)kq*8)*I_ + n0 + c0;
  const float* usrc = uw + ((size_t)e*H_ + (size_t)kq*8)*I_ + n0 + c0;
  const int bslot = (kq ^ (lane & 7)) << 4;
  const int boff0 = c0*128 + bslot;
  const int boff1 = (c0+1)*128 + bslot;

  float2 vg[8], vu[8];
  f32x4 accg[4][2], accu[4][2];
#pragma unroll
  for (int i = 0; i < 4; ++i)
#pragma unroll
    for (int j = 0; j < 2; ++j) {
      accg[i][j] = (f32x4){0.f,0.f,0.f,0.f};
      accu[i][j] = (f32x4){0.f,0.f,0.f,0.f};
    }

  auto PF = [&](int k0) {     // issue weight loads (no wait)
#pragma unroll
    for (int kr = 0; kr < 8; ++kr) {
      vg[kr] = *(const float2*)(gsrc + (size_t)(k0 + kr) * I_);
      vu[kr] = *(const float2*)(usrc + (size_t)(k0 + kr) * I_);
    }
  };
  auto GLDA = [&](int k0, int p) {
#pragma unroll
    for (int i = 0; i < 2; ++i)
      gld_lds16(asrc[i] + k0, As + p*8192 + adoff[i]);
  };
  auto CVW = [&](int p) {     // convert prefetched regs -> LDS buffer p
    BF8 pg0, pg1, pu0, pu1;
#pragma unroll
    for (int j = 0; j < 8; ++j) {
      pg0.b[j] = (__bf16)vg[j].x; pg1.b[j] = (__bf16)vg[j].y;
      pu0.b[j] = (__bf16)vu[j].x; pu1.b[j] = (__bf16)vu[j].y;
    }
    char* bg = (char*)(Bgs + p*8192);
    char* bu = (char*)(Bus + p*8192);
    *(uint4*)(bg + boff0) = pg0.q; *(uint4*)(bg + boff1) = pg1.q;
    *(uint4*)(bu + boff0) = pu0.q; *(uint4*)(bu + boff1) = pu1.q;
  };
  auto COMPUTE = [&](int p) {
    const char* Ap  = (const char*)(As  + p*8192);
    const char* Bgp = (const char*)(Bgs + p*8192);
    const char* Bup = (const char*)(Bus + p*8192);
#pragma unroll
    for (int kk = 0; kk < 2; ++kk) {
      const int ks = kk*4 + (lane >> 4);
      bf16x8 a[4], bg[2], bu[2];
#pragma unroll
      for (int mi = 0; mi < 4; ++mi) {
        int row = wr + mi*16 + (lane & 15);
        a[mi] = *(const bf16x8*)(Ap + row*128 + ((ks ^ (row & 7)) << 4));
      }
#pragma unroll
      for (int ni = 0; ni < 2; ++ni) {
        int col = wc + ni*16 + (lane & 15);
        int sw = col*128 + ((ks ^ ((col >> 1) & 7)) << 4);
        bg[ni] = *(const bf16x8*)(Bgp + sw);
        bu[ni] = *(const bf16x8*)(Bup + sw);
      }
#pragma unroll
      for (int mi = 0; mi < 4; ++mi)
#pragma unroll
        for (int ni = 0; ni < 2; ++ni) {
          accg[mi][ni] = __builtin_amdgcn_mfma_f32_16x16x32_bf16(a[mi], bg[ni], accg[mi][ni], 0, 0, 0);
          accu[mi][ni] = __builtin_amdgcn_mfma_f32_16x16x32_bf16(a[mi], bu[ni], accu[mi][ni], 0, 0, 0);
        }
    }
  };

  // pipeline: buf[p] ready; pf regs hold B(k+1); A(k+1) in flight -> buf[1-p]
  PF(0); GLDA(0, 0);
  CVW(0);
  __syncthreads();
  PF(BK); GLDA(BK, 1);
  int p = 0;
#pragma unroll 1
  for (int kt = 0; kt < NKG; ++kt) {
    COMPUTE(p);
    if (kt + 1 < NKG) CVW(1 - p);    // waits pf (in flight across COMPUTE)
    __syncthreads();                 // buf[1-p] complete; buf[p] free
    if (kt + 2 < NKG) { PF((kt + 2) * BK); GLDA((kt + 2) * BK, p); }
    p ^= 1;
  }

  const int rsub = (lane >> 4) * 4;
  const int csub = lane & 15;
#pragma unroll
  for (int mi = 0; mi < 4; ++mi)
#pragma unroll
    for (int j = 0; j < 4; ++j) {
      int rl = wr + mi*16 + rsub + j;
      if (m0 + rl < cnt) {
        size_t orow = (size_t)(off + m0 + rl) * I_ + n0 + wc + csub;
#pragma unroll
        for (int ni = 0; ni < 2; ++ni) {
          float g = accg[mi][ni][j];
          float u = accu[mi][ni][j];
          float sg = g / (1.0f + __expf(-g));
          act[orow + ni*16] = (__bf16)(sg * u);
        }
      }
    }
}

// ---------------- phase 3: down GEMM -> rowbuf (f32) ----------------
__global__ __launch_bounds__(512, 1) void down_kernel(
    const __bf16* __restrict__ act, const float* __restrict__ dw,
    const int* __restrict__ counts, const int* __restrict__ offsets,
    const int* __restrict__ tile_e, const int* __restrict__ tile_m,
    float* __restrict__ rowbuf)
{
  extern __shared__ __bf16 smem[];
  __bf16* As = smem;               // [2][8192]
  __bf16* Bs = smem + 16384;       // [2][8192]

  const int id = blockIdx.x;                    // [0, 384)
  const int w  = (id & 7) * 48 + (id >> 3);
  const int tt = w % MAXT;
  const int ny = w / MAXT;                      // [0, 16)
  const int e  = tile_e[tt];
  const int m0 = tile_m[tt];
  const int cnt = counts[e];
  if (m0 >= cnt) return;
  const int off = offsets[e];
  const int n0 = ny * BN;

  const int tid  = threadIdx.x;
  const int lane = tid & 63;
  const int wave = tid >> 6;
  const int wr = (wave >> 2) * 64;
  const int wc = (wave & 3) * 32;

  const __bf16* asrc[2];
  int adoff[2];
#pragma unroll
  for (int i = 0; i < 2; ++i) {
    int f = i*512 + tid;
    int r = f >> 3, cs = f & 7;
    int rr = m0 + r; if (rr >= cnt) rr = cnt - 1;
    asrc[i] = act + (size_t)(off + rr) * I_ + ((cs ^ (r & 7)) << 3);
    adoff[i] = f * 8;
  }

  const int c0 = (tid & 63) * 2;
  const int kq = wave;
  const float* dsrc = dw + ((size_t)e*I_ + (size_t)kq*8)*H_ + n0 + c0;
  const int bslot = (kq ^ (lane & 7)) << 4;
  const int boff0 = c0*128 + bslot;
  const int boff1 = (c0+1)*128 + bslot;

  float2 vd[8];
  f32x4 acc[4][2];
#pragma unroll
  for (int i = 0; i < 4; ++i)
#pragma unroll
    for (int j = 0; j < 2; ++j) acc[i][j] = (f32x4){0.f,0.f,0.f,0.f};

  auto PF = [&](int k0) {
#pragma unroll
    for (int kr = 0; kr < 8; ++kr)
      vd[kr] = *(const float2*)(dsrc + (size_t)(k0 + kr) * H_);
  };
  auto GLDA = [&](int k0, int p) {
#pragma unroll
    for (int i = 0; i < 2; ++i)
      gld_lds16(asrc[i] + k0, As + p*8192 + adoff[i]);
  };
  auto CVW = [&](int p) {
    BF8 p0, p1;
#pragma unroll
    for (int j = 0; j < 8; ++j) { p0.b[j] = (__bf16)vd[j].x; p1.b[j] = (__bf16)vd[j].y; }
    char* bb = (char*)(Bs + p*8192);
    *(uint4*)(bb + boff0) = p0.q; *(uint4*)(bb + boff1) = p1.q;
  };
  auto COMPUTE = [&](int p) {
    const char* Ap = (const char*)(As + p*8192);
    const char* Bp = (const char*)(Bs + p*8192);
#pragma unroll
    for (int kk = 0; kk < 2; ++kk) {
      const int ks = kk*4 + (lane >> 4);
      bf16x8 a[4], b[2];
#pragma unroll
      for (int mi = 0; mi < 4; ++mi) {
        int row = wr + mi*16 + (lane & 15);
        a[mi] = *(const bf16x8*)(Ap + row*128 + ((ks ^ (row & 7)) << 4));
      }
#pragma unroll
      for (int ni = 0; ni < 2; ++ni) {
        int col = wc + ni*16 + (lane & 15);
        b[ni] = *(const bf16x8*)(Bp + col*128 + ((ks ^ ((col >> 1) & 7)) << 4));
      }
#pragma unroll
      for (int mi = 0; mi < 4; ++mi)
#pragma unroll
        for (int ni = 0; ni < 2; ++ni)
          acc[mi][ni] = __builtin_amdgcn_mfma_f32_16x16x32_bf16(a[mi], b[ni], acc[mi][ni], 0, 0, 0);
    }
  };

  PF(0); GLDA(0, 0);
  CVW(0);
  __syncthreads();
  PF(BK); GLDA(BK, 1);
  int p = 0;
#pragma unroll 1
  for (int kt = 0; kt < NKD; ++kt) {
    COMPUTE(p);
    if (kt + 1 < NKD) CVW(1 - p);
    __syncthreads();
    if (kt + 2 < NKD) { PF((kt + 2) * BK); GLDA((kt + 2) * BK, p); }
    p ^= 1;
  }

  const int rsub = (lane >> 4) * 4;
  const int csub = lane & 15;
#pragma unroll
  for (int mi = 0; mi < 4; ++mi)
#pragma unroll
    for (int j = 0; j < 4; ++j) {
      int rl = wr + mi*16 + rsub + j;
      if (m0 + rl < cnt) {
        size_t orow = (size_t)(off + m0 + rl) * H_ + n0 + wc + csub;
#pragma unroll
        for (int ni = 0; ni < 2; ++ni)
          rowbuf[orow + ni*16] = acc[mi][ni][j];
      }
    }
}

// ---------------- phase 4: weighted combine ----------------
__global__ void combine_kernel(const float* __restrict__ ew, const int* __restrict__ row_of,
                               const float* __restrict__ rowbuf, float* __restrict__ out) {
  int idx = blockIdx.x * 256 + threadIdx.x;   // over B_*H_/4
  int t  = idx >> 9;                          // H_/4 = 512
  int h4 = idx & 511;
  float w0 = ew[t*2+0], w1 = ew[t*2+1];
  int r0 = row_of[t*2+0], r1 = row_of[t*2+1];
  float4 a = *(const float4*)(rowbuf + (size_t)r0*H_ + h4*4);
  float4 b = *(const float4*)(rowbuf + (size_t)r1*H_ + h4*4);
  float4 o;
  o.x = w0*a.x + w1*b.x; o.y = w0*a.y + w1*b.y;
  o.z = w0*a.z + w1*b.z; o.w = w0*a.w + w1*b.w;
  *(float4*)(out + (size_t)idx*4) = o;
}

extern "C" void kernel_launch(void* const* d_in, const int* in_sizes, int n_in,
                              void* d_out, int out_size, void* d_ws, size_t ws_size,
                              hipStream_t stream) {
  const float* x   = (const float*)d_in[0];
  const int*   ids = (const int*)d_in[1];
  const float* ew  = (const float*)d_in[2];
  const float* gw  = (const float*)d_in[3];
  const float* uw  = (const float*)d_in[4];
  const float* dwn = (const float*)d_in[5];
  float* out = (float*)d_out;

  char* ws = (char*)d_ws;
  int* counts  = (int*)ws;          // 8
  int* offsets = counts + 8;        // 8
  int* tlist   = offsets + 8;       // NROWS
  int* row_of  = tlist + NROWS;     // NROWS
  int* tile_e  = row_of + NROWS;    // MAXT
  int* tile_m  = tile_e + MAXT;     // MAXT
  __bf16* xb   = (__bf16*)(ws + 32768);
  __bf16* act  = (__bf16*)(ws + 32768 + (size_t)B_*H_*2);
  float* rowbuf = (float*)(ws + 32768 + (size_t)B_*H_*2 + (size_t)NROWS*I_*2);

  hipFuncSetAttribute(reinterpret_cast<const void*>(&gateup_kernel),
                      hipFuncAttributeMaxDynamicSharedMemorySize, 98304);
  hipFuncSetAttribute(reinterpret_cast<const void*>(&down_kernel),
                      hipFuncAttributeMaxDynamicSharedMemorySize, 65536);

  cvtx_kernel<<<B_*H_/(256*8), 256, 0, stream>>>(x, xb);
  route_kernel<<<1, 256, 0, stream>>>(ids, counts, offsets, tlist, row_of, tile_e, tile_m);

  gateup_kernel<<<MAXT*(I_/BN), 512, 98304, stream>>>(xb, gw, uw, counts, offsets, tlist,
                                                      tile_e, tile_m, act);

  down_kernel<<<MAXT*(H_/BN), 512, 65536, stream>>>(act, dwn, counts, offsets,
                                                    tile_e, tile_m, rowbuf);

  combine_kernel<<<(B_*H_/4)/256, 256, 0, stream>>>(ew, row_of, rowbuf, out);
}